// Round 1
// baseline (793.049 us; speedup 1.0000x reference)
//
#include <hip/hip_runtime.h>
#include <hip/hip_bf16.h>

// Problem constants (from reference): B=32, S=2048, D=768, NL=512, NF=64
#define Bq 32
#define Sq 2048
#define Dq 768
#define NLq 512
#define NFq 64

typedef unsigned short u16;
typedef __attribute__((ext_vector_type(4))) unsigned short us4;
typedef __attribute__((ext_vector_type(8))) unsigned short us8;
typedef __attribute__((ext_vector_type(8))) short s16x8;
typedef __attribute__((ext_vector_type(4))) float f32x4;

static __device__ __forceinline__ u16 f2bf(float f) {
  unsigned int u = __builtin_bit_cast(unsigned int, f);
  u += 0x7fffu + ((u >> 16) & 1u);  // round-to-nearest-even
  return (u16)(u >> 16);
}

// K0: W [K,N] fp32 row-major -> Wt [N,K] bf16 row-major (coalesced write)
__global__ __launch_bounds__(256) void wt_kernel(const float* __restrict__ W,
                                                 u16* __restrict__ Wt) {
  int idx = blockIdx.x * 256 + threadIdx.x;     // [0, 768*768)
  int n = idx / Dq, k = idx % Dq;
  Wt[idx] = f2bf(W[(size_t)k * Dq + n]);
}

// K1: C[M,N] = A[M,K] @ Wt^T + bias, bf16 MFMA, M=65536, N=K=768
// tile 128x128x32, 256 threads (4 waves, each 64x64 = 4x4 frags of 16x16x32)
__global__ __launch_bounds__(256) void gemm_kernel(const float* __restrict__ A,
                                                   const u16* __restrict__ Wt,
                                                   const float* __restrict__ bias,
                                                   float* __restrict__ C) {
  __shared__ u16 As[128 * 32];  // [m][k]
  __shared__ u16 Bs[128 * 32];  // [n][k]
  const int tid = threadIdx.x;
  const int gn0 = blockIdx.x * 128;  // x fastest: 6 N-tiles share A slab via L2
  const int gm0 = blockIdx.y * 128;
  const int wave = tid >> 6, lane = tid & 63;
  const int lm = lane & 15, quad = lane >> 4;
  const int wm = (wave & 1) * 64, wn = (wave >> 1) * 64;
  const int ar = tid >> 3, aq = tid & 7;  // A staging: 8 lanes/row
  const int bn = tid >> 2, bc = tid & 3;  // B staging: 4 lanes/row

  f32x4 acc[4][4] = {};

  for (int k0 = 0; k0 < Dq; k0 += 32) {
    // stage A: 128 rows x 32 k fp32 -> bf16
#pragma unroll
    for (int p = 0; p < 4; ++p) {
      const int row = p * 32 + ar;
      const float4 v = *(const float4*)(A + (size_t)(gm0 + row) * Dq + k0 + aq * 4);
      us4 o;
      o.x = f2bf(v.x); o.y = f2bf(v.y); o.z = f2bf(v.z); o.w = f2bf(v.w);
      *(us4*)&As[row * 32 + aq * 4] = o;
    }
    // stage B: 128 rows (n) x 32 k bf16, already transposed in Wt
#pragma unroll
    for (int p = 0; p < 2; ++p) {
      const int row = p * 64 + bn;
      const us8 v = *(const us8*)(Wt + (size_t)(gn0 + row) * Dq + k0 + bc * 8);
      *(us8*)&Bs[row * 32 + bc * 8] = v;
    }
    __syncthreads();

    s16x8 af[4], bfr[4];
#pragma unroll
    for (int i = 0; i < 4; ++i)
      af[i] = *(const s16x8*)&As[(wm + i * 16 + lm) * 32 + quad * 8];
#pragma unroll
    for (int i = 0; i < 4; ++i)
      bfr[i] = *(const s16x8*)&Bs[(wn + i * 16 + lm) * 32 + quad * 8];
#pragma unroll
    for (int mi = 0; mi < 4; ++mi)
#pragma unroll
      for (int ni = 0; ni < 4; ++ni)
        acc[mi][ni] = __builtin_amdgcn_mfma_f32_16x16x32_bf16(af[mi], bfr[ni],
                                                              acc[mi][ni], 0, 0, 0);
    __syncthreads();
  }

  // epilogue: D layout col=lane&15, row=quad*4+r
#pragma unroll
  for (int ni = 0; ni < 4; ++ni) {
    const int gn = gn0 + wn + ni * 16 + lm;
    const float bv = bias[gn];
#pragma unroll
    for (int mi = 0; mi < 4; ++mi) {
#pragma unroll
      for (int r = 0; r < 4; ++r) {
        const int gm = gm0 + wm + mi * 16 + quad * 4 + r;
        C[(size_t)gm * Dq + gn] = acc[mi][ni][r] + bv;
      }
    }
  }
}

// K2: exclusive prefix sum over S per (b,d) column. csum[b,0,:]=0.
__global__ __launch_bounds__(64) void csum_kernel(const float* __restrict__ tok,
                                                  float* __restrict__ csum) {
  const int blk = blockIdx.x;            // B * 12
  const int b = blk / 12;
  const int d = (blk % 12) * 64 + threadIdx.x;
  const float* src = tok + (size_t)b * Sq * Dq + d;
  float* dst = csum + (size_t)b * (Sq + 1) * Dq + d;
  dst[0] = 0.f;
  float run = 0.f;
  for (int s0 = 0; s0 < Sq; s0 += 16) {
    float v[16];
#pragma unroll
    for (int i = 0; i < 16; ++i) v[i] = src[(size_t)(s0 + i) * Dq];
#pragma unroll
    for (int i = 0; i < 16; ++i) {
      run += v[i];
      dst[(size_t)(s0 + i + 1) * Dq] = run;
    }
  }
}

// K3: line_emb[b,n,:] = (csum[end]-csum[start])/len (0 if empty), fused with
// exclusive cumsum over lines -> lcsum[b,0..NL,:]
__global__ __launch_bounds__(64) void line_kernel(const float* __restrict__ csum,
                                                  const int* __restrict__ lb,
                                                  float* __restrict__ lemb,
                                                  float* __restrict__ lcsum) {
  __shared__ int sb[NLq * 2];
  const int tid = threadIdx.x;
  const int blk = blockIdx.x;
  const int b = blk / 12;
  const int d = (blk % 12) * 64 + tid;
  const int4* lb4 = (const int4*)(lb + (size_t)b * NLq * 2);
#pragma unroll
  for (int i = tid; i < NLq * 2 / 4; i += 64) ((int4*)sb)[i] = lb4[i];
  __syncthreads();

  const float* cs = csum + (size_t)b * (Sq + 1) * Dq + d;
  float* le = lemb + (size_t)b * NLq * Dq + d;
  float* lc = lcsum + (size_t)b * (NLq + 1) * Dq + d;
  lc[0] = 0.f;
  float run = 0.f;
  for (int n0 = 0; n0 < NLq; n0 += 8) {
    float ve[8], vs[8];
    int len[8];
#pragma unroll
    for (int i = 0; i < 8; ++i) {
      const int s0 = sb[2 * (n0 + i)], s1 = sb[2 * (n0 + i) + 1];
      len[i] = s1 - s0;
      vs[i] = cs[(size_t)s0 * Dq];
      ve[i] = cs[(size_t)s1 * Dq];
    }
#pragma unroll
    for (int i = 0; i < 8; ++i) {
      const float v = len[i] > 0 ? (ve[i] - vs[i]) / (float)len[i] : 0.f;
      le[(size_t)(n0 + i) * Dq] = v;
      run += v;
      lc[(size_t)(n0 + i + 1) * Dq] = run;
    }
  }
}

// K4: func_emb from line csum gather + file_emb = mean over 64 functions
__global__ __launch_bounds__(64) void func_kernel(const float* __restrict__ lcsum,
                                                  const int* __restrict__ fb,
                                                  float* __restrict__ femb,
                                                  float* __restrict__ file) {
  __shared__ int sb[NFq * 2];
  const int tid = threadIdx.x;
  const int blk = blockIdx.x;
  const int b = blk / 12;
  const int d = (blk % 12) * 64 + tid;
  if (tid < NFq * 2 / 4) ((int4*)sb)[tid] = ((const int4*)(fb + (size_t)b * NFq * 2))[tid];
  __syncthreads();

  const float* lc = lcsum + (size_t)b * (NLq + 1) * Dq + d;
  float* fe = femb + (size_t)b * NFq * Dq + d;
  float acc = 0.f;
#pragma unroll 8
  for (int f = 0; f < NFq; ++f) {
    const int l0 = sb[2 * f], l1 = sb[2 * f + 1];
    const float v = l1 > l0 ? (lc[(size_t)l1 * Dq] - lc[(size_t)l0 * Dq]) / (float)(l1 - l0)
                            : 0.f;
    fe[(size_t)f * Dq] = v;
    acc += v;
  }
  file[(size_t)b * Dq + d] = acc * (1.f / (float)NFq);
}

extern "C" void kernel_launch(void* const* d_in, const int* in_sizes, int n_in,
                              void* d_out, int out_size, void* d_ws, size_t ws_size,
                              hipStream_t stream) {
  const float* hs   = (const float*)d_in[0];  // [B,S,D] fp32
  const float* W    = (const float*)d_in[1];  // [D,D] fp32
  const float* bias = (const float*)d_in[2];  // [D] fp32
  const int* lb     = (const int*)d_in[3];    // [B,NL,2] int32
  const int* fb     = (const int*)d_in[4];    // [B,NF,2] int32

  float* out = (float*)d_out;
  float* token = out;                                        // B*S*D
  float* line  = token + (size_t)Bq * Sq * Dq;               // B*NL*D
  float* func  = line + (size_t)Bq * NLq * Dq;               // B*NF*D
  float* file  = func + (size_t)Bq * NFq * Dq;               // B*D

  float* csum  = (float*)d_ws;                               // B*(S+1)*D fp32
  float* lcsum = csum + (size_t)Bq * (Sq + 1) * Dq;          // B*(NL+1)*D fp32
  u16* Wt      = (u16*)(lcsum + (size_t)Bq * (NLq + 1) * Dq);// D*D bf16

  wt_kernel<<<(Dq * Dq) / 256, 256, 0, stream>>>(W, Wt);
  gemm_kernel<<<dim3(Dq / 128, (Bq * Sq) / 128), 256, 0, stream>>>(hs, Wt, bias, token);
  csum_kernel<<<Bq * (Dq / 64), 64, 0, stream>>>(token, csum);
  line_kernel<<<Bq * (Dq / 64), 64, 0, stream>>>(csum, lb, line, lcsum);
  func_kernel<<<Bq * (Dq / 64), 64, 0, stream>>>(lcsum, fb, func, file);
}

// Round 2
// 676.825 us; speedup vs baseline: 1.1717x; 1.1717x over previous
//
#include <hip/hip_runtime.h>
#include <hip/hip_bf16.h>

// Problem constants: B=32, S=2048, D=768, NL=512, NF=64
#define Bq 32
#define Sq 2048
#define Dq 768
#define NLq 512
#define NFq 64
#define SCHUNKS 16   // S / 128
#define LCHUNKS 8    // NL / 64

typedef unsigned short u16;
typedef __attribute__((ext_vector_type(4))) unsigned short us4;
typedef __attribute__((ext_vector_type(8))) short s16x8;
typedef __attribute__((ext_vector_type(4))) float f32x4;

static __device__ __forceinline__ u16 f2bf(float f) {
  unsigned int u = __builtin_bit_cast(unsigned int, f);
  u += 0x7fffu + ((u >> 16) & 1u);  // round-to-nearest-even
  return (u16)(u >> 16);
}

// async global->LDS, 16 B per lane; LDS dest = wave-uniform base + lane*16
static __device__ __forceinline__ void gload16(const void* g, void* l) {
  __builtin_amdgcn_global_load_lds(
      (const __attribute__((address_space(1))) unsigned int*)g,
      (__attribute__((address_space(3))) unsigned int*)l, 16, 0, 0);
}

// K0a: hidden_states fp32 [M,K] -> bf16 (for MFMA A operand)
__global__ __launch_bounds__(256) void cvta_kernel(const float* __restrict__ hs,
                                                   u16* __restrict__ Abf) {
  const size_t i = (size_t)blockIdx.x * 256 + threadIdx.x;  // over float4s
  const float4 v = ((const float4*)hs)[i];
  us4 o;
  o.x = f2bf(v.x); o.y = f2bf(v.y); o.z = f2bf(v.z); o.w = f2bf(v.w);
  ((us4*)Abf)[i] = o;
}

// K0b: W [K,N] fp32 row-major -> Wt [N,K] bf16 row-major
__global__ __launch_bounds__(256) void wt_kernel(const float* __restrict__ W,
                                                 u16* __restrict__ Wt) {
  int idx = blockIdx.x * 256 + threadIdx.x;
  int n = idx / Dq, k = idx % Dq;
  Wt[idx] = f2bf(W[(size_t)k * Dq + n]);
}

// K1: C[M,N] = A@Wt^T + bias (bf16 MFMA, m97 structure: global_load_lds w=16,
// 2-barrier K-loop). Also emits per-128-row column sums into part16 for the
// chunked token cumsum (fused epilogue reduction).
__global__ __launch_bounds__(256) void gemm_kernel(const u16* __restrict__ Abf,
                                                   const u16* __restrict__ Wt,
                                                   const float* __restrict__ bias,
                                                   float* __restrict__ C,
                                                   float* __restrict__ part16) {
  __shared__ u16 As[128 * 32];  // [m][k], linear (global_load_lds needs no pad)
  __shared__ u16 Bs[128 * 32];  // [n][k]
  __shared__ float ps[2][128];
  const int tid = threadIdx.x;
  const int gn0 = blockIdx.x * 128;
  const int gm0 = blockIdx.y * 128;
  const int wave = tid >> 6, lane = tid & 63;
  const int lm = lane & 15, quad = lane >> 4;
  const int wm = (wave & 1) * 64, wn = (wave >> 1) * 64;

  // staging addresses: lane covers row = tid/4, 16B chunk (tid&3) within 64B row
  const char* ga0 = (const char*)Abf + (size_t)(gm0 + (tid >> 2)) * (Dq * 2) + (tid & 3) * 16;
  const char* ga1 = ga0 + (size_t)64 * (Dq * 2);
  const char* gb0 = (const char*)Wt + (size_t)(gn0 + (tid >> 2)) * (Dq * 2) + (tid & 3) * 16;
  const char* gb1 = gb0 + (size_t)64 * (Dq * 2);
  char* lA = (char*)As + wave * 1024;  // wave-uniform; HW adds lane*16
  char* lB = (char*)Bs + wave * 1024;

  f32x4 acc[4][4] = {};

  for (int kk = 0; kk < Dq / 32; ++kk) {
    __syncthreads();  // prev tile's ds_reads done
    gload16(ga0, lA);
    gload16(ga1, lA + 4096);
    gload16(gb0, lB);
    gload16(gb1, lB + 4096);
    ga0 += 64; ga1 += 64; gb0 += 64; gb1 += 64;
    __syncthreads();  // vmcnt(0) drain: tile resident

    s16x8 af[4], bfr[4];
#pragma unroll
    for (int i = 0; i < 4; ++i)
      af[i] = *(const s16x8*)&As[(wm + i * 16 + lm) * 32 + quad * 8];
#pragma unroll
    for (int i = 0; i < 4; ++i)
      bfr[i] = *(const s16x8*)&Bs[(wn + i * 16 + lm) * 32 + quad * 8];
#pragma unroll
    for (int mi = 0; mi < 4; ++mi)
#pragma unroll
      for (int ni = 0; ni < 4; ++ni)
        acc[mi][ni] = __builtin_amdgcn_mfma_f32_16x16x32_bf16(af[mi], bfr[ni],
                                                              acc[mi][ni], 0, 0, 0);
  }

  // epilogue: D layout col=lane&15, row=quad*4+r; also column sums for csum
#pragma unroll
  for (int ni = 0; ni < 4; ++ni) {
    const int gn = gn0 + wn + ni * 16 + lm;
    const float bv = bias[gn];
    float psum = 0.f;
#pragma unroll
    for (int mi = 0; mi < 4; ++mi) {
#pragma unroll
      for (int r = 0; r < 4; ++r) {
        const int gm = gm0 + wm + mi * 16 + quad * 4 + r;
        const float cv = acc[mi][ni][r] + bv;
        C[(size_t)gm * Dq + gn] = cv;
        psum += cv;
      }
    }
    psum += __shfl_xor(psum, 16);
    psum += __shfl_xor(psum, 32);
    if (lane < 16) ps[wave & 1][wn + ni * 16 + lm] = psum;
  }
  __syncthreads();
  if (tid < 128) {
    const int b = gm0 >> 11;            // /2048
    const int sc = (gm0 >> 7) & 15;     // 128-row chunk within b
    part16[((size_t)b * SCHUNKS + sc) * Dq + gn0 + tid] = ps[0][tid] + ps[1][tid];
  }
}

// K2: in-place exclusive scan over C chunks per (b,d) column
__global__ __launch_bounds__(256) void scan_kernel(float* __restrict__ p, int C) {
  const int idx = blockIdx.x * 256 + threadIdx.x;  // B*D = 24576
  const int b = idx / Dq, d = idx % Dq;
  float run = 0.f;
  for (int c = 0; c < C; ++c) {
    const size_t o = ((size_t)b * C + c) * Dq + d;
    const float v = p[o];
    p[o] = run;
    run += v;
  }
}

// K3: csum[b, sc*128+1 .. sc*128+128, d] from token + scanned chunk offsets
__global__ __launch_bounds__(256) void csum_kernel(const float* __restrict__ tok,
                                                   const float* __restrict__ part16,
                                                   float* __restrict__ csum) {
  const int sc = blockIdx.x, dc = blockIdx.y, b = blockIdx.z;
  const int d = dc * 256 + threadIdx.x;
  const float* src = tok + ((size_t)b * Sq + sc * 128) * Dq + d;
  float* dst = csum + ((size_t)b * (Sq + 1) + sc * 128 + 1) * Dq + d;
  float run = part16[((size_t)b * SCHUNKS + sc) * Dq + d];
  if (sc == 0) csum[(size_t)b * (Sq + 1) * Dq + d] = 0.f;
  for (int s0 = 0; s0 < 128; s0 += 8) {
    float v[8];
#pragma unroll
    for (int i = 0; i < 8; ++i) v[i] = src[(size_t)(s0 + i) * Dq];
#pragma unroll
    for (int i = 0; i < 8; ++i) {
      run += v[i];
      dst[(size_t)(s0 + i) * Dq] = run;
    }
  }
}

// K4: line means (64 lines per block) + per-chunk line sums for lcsum scan
__global__ __launch_bounds__(64) void line_kernel(const float* __restrict__ csum,
                                                  const int* __restrict__ lb,
                                                  float* __restrict__ lemb,
                                                  float* __restrict__ lpart) {
  __shared__ int sb[128];
  const int lc = blockIdx.x, d64 = blockIdx.y, b = blockIdx.z;
  const int tid = threadIdx.x;
  if (tid < 32)
    ((int4*)sb)[tid] = ((const int4*)(lb + ((size_t)b * NLq + lc * 64) * 2))[tid];
  __syncthreads();
  const int d = d64 * 64 + tid;
  const float* cs = csum + (size_t)b * (Sq + 1) * Dq + d;
  float* le = lemb + ((size_t)b * NLq + lc * 64) * Dq + d;
  float sum = 0.f;
  for (int n0 = 0; n0 < 64; n0 += 8) {
    float vs[8], ve[8];
    int len[8];
#pragma unroll
    for (int i = 0; i < 8; ++i) {
      const int s0 = sb[2 * (n0 + i)], s1 = sb[2 * (n0 + i) + 1];
      len[i] = s1 - s0;
      vs[i] = cs[(size_t)s0 * Dq];
      ve[i] = cs[(size_t)s1 * Dq];
    }
#pragma unroll
    for (int i = 0; i < 8; ++i) {
      const float v = len[i] > 0 ? (ve[i] - vs[i]) / (float)len[i] : 0.f;
      le[(size_t)(n0 + i) * Dq] = v;
      sum += v;
    }
  }
  lpart[((size_t)b * LCHUNKS + lc) * Dq + d] = sum;
}

// K5: lcsum rows from lemb + scanned chunk offsets
__global__ __launch_bounds__(256) void lcsum_kernel(const float* __restrict__ lemb,
                                                    const float* __restrict__ lpart,
                                                    float* __restrict__ lcsum) {
  const int lc = blockIdx.x, dc = blockIdx.y, b = blockIdx.z;
  const int d = dc * 256 + threadIdx.x;
  const float* src = lemb + ((size_t)b * NLq + lc * 64) * Dq + d;
  float* dst = lcsum + ((size_t)b * (NLq + 1) + lc * 64 + 1) * Dq + d;
  float run = lpart[((size_t)b * LCHUNKS + lc) * Dq + d];
  if (lc == 0) lcsum[(size_t)b * (NLq + 1) * Dq + d] = 0.f;
  for (int n0 = 0; n0 < 64; n0 += 8) {
    float v[8];
#pragma unroll
    for (int i = 0; i < 8; ++i) v[i] = src[(size_t)(n0 + i) * Dq];
#pragma unroll
    for (int i = 0; i < 8; ++i) {
      run += v[i];
      dst[(size_t)(n0 + i) * Dq] = run;
    }
  }
}

// K6: func_emb from lcsum gather + file_emb = mean over 64 functions
__global__ __launch_bounds__(64) void func_kernel(const float* __restrict__ lcsum,
                                                  const int* __restrict__ fb,
                                                  float* __restrict__ femb,
                                                  float* __restrict__ file) {
  __shared__ int sb[NFq * 2];
  const int tid = threadIdx.x;
  const int d64 = blockIdx.x, b = blockIdx.y;
  const int d = d64 * 64 + tid;
  if (tid < NFq * 2 / 4)
    ((int4*)sb)[tid] = ((const int4*)(fb + (size_t)b * NFq * 2))[tid];
  __syncthreads();
  const float* lc = lcsum + (size_t)b * (NLq + 1) * Dq + d;
  float* fe = femb + (size_t)b * NFq * Dq + d;
  float acc = 0.f;
#pragma unroll 8
  for (int f = 0; f < NFq; ++f) {
    const int l0 = sb[2 * f], l1 = sb[2 * f + 1];
    const float v = l1 > l0 ? (lc[(size_t)l1 * Dq] - lc[(size_t)l0 * Dq]) / (float)(l1 - l0)
                            : 0.f;
    fe[(size_t)f * Dq] = v;
    acc += v;
  }
  file[(size_t)b * Dq + d] = acc * (1.f / (float)NFq);
}

extern "C" void kernel_launch(void* const* d_in, const int* in_sizes, int n_in,
                              void* d_out, int out_size, void* d_ws, size_t ws_size,
                              hipStream_t stream) {
  const float* hs   = (const float*)d_in[0];  // [B,S,D] fp32
  const float* W    = (const float*)d_in[1];  // [D,D] fp32
  const float* bias = (const float*)d_in[2];  // [D] fp32
  const int* lb     = (const int*)d_in[3];    // [B,NL,2] int32
  const int* fb     = (const int*)d_in[4];    // [B,NF,2] int32

  float* out = (float*)d_out;
  float* token = out;                                         // B*S*D
  float* line  = token + (size_t)Bq * Sq * Dq;                // B*NL*D
  float* func  = line + (size_t)Bq * NLq * Dq;                // B*NF*D
  float* file  = func + (size_t)Bq * NFq * Dq;                // B*D

  // Workspace layout (253,120,512 B total) with stream-order-safe aliasing:
  //   [0, 201.5MB)  csum fp32          | Abf bf16 (100.7MB, dead before csum)
  //   [201.5, 251.9) lcsum fp32        | part16 (1.57MB, dead before lcsum)
  //   [251.9, 253.1) Wt bf16 (1.18MB)  | lpart (0.79MB, dead... written after Wt reads)
  char* ws = (char*)d_ws;
  float* csum   = (float*)ws;
  u16*   Abf    = (u16*)ws;
  float* lcsum  = (float*)(ws + 201498624);
  float* part16 = lcsum;
  u16*   Wt     = (u16*)(ws + 201498624 + 50442240);
  float* lpart  = (float*)Wt;

  cvta_kernel<<<(Bq * Sq * Dq / 4) / 256, 256, 0, stream>>>(hs, Abf);
  wt_kernel<<<(Dq * Dq) / 256, 256, 0, stream>>>(W, Wt);
  gemm_kernel<<<dim3(Dq / 128, (Bq * Sq) / 128), 256, 0, stream>>>(Abf, Wt, bias, token, part16);
  scan_kernel<<<(Bq * Dq) / 256, 256, 0, stream>>>(part16, SCHUNKS);
  csum_kernel<<<dim3(SCHUNKS, 3, Bq), 256, 0, stream>>>(token, part16, csum);
  line_kernel<<<dim3(LCHUNKS, 12, Bq), 64, 0, stream>>>(csum, lb, line, lpart);
  scan_kernel<<<(Bq * Dq) / 256, 256, 0, stream>>>(lpart, LCHUNKS);
  lcsum_kernel<<<dim3(LCHUNKS, 3, Bq), 256, 0, stream>>>(line, lpart, lcsum);
  func_kernel<<<dim3(12, Bq), 64, 0, stream>>>(lcsum, fb, func, file);
}